// Round 18
// baseline (187.114 us; speedup 1.0000x reference)
//
#include <hip/hip_runtime.h>
#include <hip/hip_bf16.h>
#include <stdint.h>

#define S_LEN 4096
#define D_DIM 256
#define NBATCH 4
#define KVBLK 32
#define NHS 64    // half-steps; pair covers 64 tiles of 32 keys

typedef unsigned short u16;
typedef float  f32x4  __attribute__((ext_vector_type(4)));
typedef __bf16 bf16x8 __attribute__((ext_vector_type(8)));
typedef __bf16 bf16x4 __attribute__((ext_vector_type(4)));
typedef short  s16x8  __attribute__((ext_vector_type(8)));
typedef short  s16x4  __attribute__((ext_vector_type(4)));

#define AS1 __attribute__((address_space(1)))
#define AS3 __attribute__((address_space(3)))

__device__ __forceinline__ f32x4 mfma16(bf16x8 a, bf16x8 b, f32x4 c) {
  return __builtin_amdgcn_mfma_f32_16x16x32_bf16(a, b, c, 0, 0, 0);
}

__device__ __forceinline__ s16x4 cvt4(float x, float y, float z, float w) {
  bf16x4 b;
  b[0] = (__bf16)x; b[1] = (__bf16)y; b[2] = (__bf16)z; b[3] = (__bf16)w;
  return __builtin_bit_cast(s16x4, b);
}

__device__ __forceinline__ void gload16(const void* g, void* l) {
  __builtin_amdgcn_global_load_lds((const AS1 unsigned int*)g,
                                   (AS3 unsigned int*)l, 16, 0, 0);
}

// ---------------------------------------------------------------------------
// R18 = R17 + __attribute__((amdgpu_waves_per_eu(4,4))).
// R16/R17 showed the allocator picks VGPR=64 (chasing 8 waves/EU) and spills
// acc[16] (WRITE_SIZE 16->35MB, MfmaUtil 21->14). launch_bounds only sets the
// LOWER occupancy bound; amdgpu_waves_per_eu(4,4) also caps the UPPER bound
// at 4 waves/EU, freeing the full 128-VGPR budget (compute needs ~88-112).
// Everything else R17/R16 verbatim (passed, absmax 9.8e-4, occupancy 45%).
// ---------------------------------------------------------------------------

__global__ void build_imgs32(const float* __restrict__ K, const float* __restrict__ V,
                             u16* __restrict__ kimg, u16* __restrict__ vimg) {
  __shared__ u16 lds[KVBLK * 264];         // V tile bf16, row stride 264 u16
  const int wg  = blockIdx.x;              // (b*128 + T), 512 WGs
  const int tid = threadIdx.x;

  // ---- K image (R13 build_kimg32 verbatim) ----
  const float* ksrc = K + (size_t)wg * KVBLK * D_DIM;
  u16*         kdst = kimg + (size_t)wg * 8192;
  #pragma unroll
  for (int i = 0; i < 4; ++i) {
    const int idx = i * 256 + tid;         // 1024 chunks of 16B
    const int k = idx >> 5, p = idx & 31;
    const int q = p ^ (k & 7);
    const float* s = ksrc + k * 256 + q * 8;
    float4 f0 = *reinterpret_cast<const float4*>(s);
    float4 f1 = *reinterpret_cast<const float4*>(s + 4);
    s16x8 v = __builtin_shufflevector(cvt4(f0.x, f0.y, f0.z, f0.w),
                                      cvt4(f1.x, f1.y, f1.z, f1.w),
                                      0, 1, 2, 3, 4, 5, 6, 7);
    *reinterpret_cast<s16x8*>(kdst + k * 256 + p * 8) = v;
  }

  // ---- V image (R13 build_vimg32 verbatim) ----
  const float* vsrc = V + (size_t)wg * KVBLK * D_DIM;
  u16*         vdst = vimg + (size_t)wg * 8192;
  #pragma unroll
  for (int i = 0; i < 4; ++i) {
    const int idx = i * 256 + tid;
    const int k = idx >> 5, q = idx & 31;
    const float* s = vsrc + k * 256 + q * 8;
    float4 f0 = *reinterpret_cast<const float4*>(s);
    float4 f1 = *reinterpret_cast<const float4*>(s + 4);
    s16x8 v = __builtin_shufflevector(cvt4(f0.x, f0.y, f0.z, f0.w),
                                      cvt4(f1.x, f1.y, f1.z, f1.w),
                                      0, 1, 2, 3, 4, 5, 6, 7);
    *reinterpret_cast<s16x8*>(&lds[k * 264 + q * 8]) = v;
  }
  __syncthreads();
  const int d = tid;                        // one output row per thread
  const int s = ((d >> 4) ^ d) & 3;
  #pragma unroll
  for (int c = 0; c < 4; ++c) {
    const int gp = c ^ s;                   // col chunk held at position c
    s16x8 o;
    #pragma unroll
    for (int ii = 0; ii < 8; ++ii) {
      const int k = 16 * (ii >> 2) + 4 * gp + (ii & 3);
      o[ii] = (short)lds[k * 264 + d];
    }
    *reinterpret_cast<s16x8*>(vdst + d * 32 + c * 8) = o;
  }
}

// ---- compute one staged 32-key tile, 1 q-slot (R13 verbatim, validated) ----
__device__ __forceinline__
void compute_tile32(const char* KsB, const char* VtB,
                    const bf16x8 (&qf)[8], f32x4 (&acc)[16],
                    float& m_run, float& l_run, int g, int h)
{
  const f32x4 fz = {0.f, 0.f, 0.f, 0.f};

  f32x4 st[2];
  st[0] = fz; st[1] = fz;
  __builtin_amdgcn_s_setprio(1);
  #pragma unroll
  for (int t = 0; t < 2; ++t) {
    const int row = t * 16 + h;
    const int sw  = (row & 7) << 4;
    #pragma unroll
    for (int dc = 0; dc < 8; ++dc) {
      s16x8 kf = *reinterpret_cast<const s16x8*>(KsB + row * 512 + ((dc * 64 + g * 16) ^ sw));
      st[t] = mfma16(__builtin_bit_cast(bf16x8, kf), qf[dc], st[t]);
    }
  }
  __builtin_amdgcn_s_setprio(0);

  float sv[8];
  #pragma unroll
  for (int t = 0; t < 2; ++t) {
    sv[t * 4 + 0] = st[t][0]; sv[t * 4 + 1] = st[t][1];
    sv[t * 4 + 2] = st[t][2]; sv[t * 4 + 3] = st[t][3];
  }
  float tmax = sv[0];
  #pragma unroll
  for (int i = 1; i < 8; ++i) tmax = fmaxf(tmax, sv[i]);
  tmax = fmaxf(tmax, __shfl_xor(tmax, 16));
  tmax = fmaxf(tmax, __shfl_xor(tmax, 32));

  if (!__all(tmax <= m_run + 8.0f)) {     // T13 defer-max
    const float mnew  = fmaxf(m_run, tmax);
    const float alpha = __expf(m_run - mnew);
    l_run *= alpha;
    float af[4];
    #pragma unroll
    for (int r = 0; r < 4; ++r) af[r] = __shfl(alpha, g * 4 + r);
    #pragma unroll
    for (int dt = 0; dt < 16; ++dt) {
      acc[dt][0] *= af[0]; acc[dt][1] *= af[1];
      acc[dt][2] *= af[2]; acc[dt][3] *= af[3];
    }
    m_run = mnew;
  }

  float psum = 0.f;
  #pragma unroll
  for (int i = 0; i < 8; ++i) { sv[i] = __expf(sv[i] - m_run); psum += sv[i]; }
  psum += __shfl_xor(psum, 16);
  psum += __shfl_xor(psum, 32);
  l_run += psum;

  bf16x8 pa;
  #pragma unroll
  for (int j = 0; j < 8; ++j) pa[j] = (__bf16)sv[j];

  __builtin_amdgcn_s_setprio(1);
  #pragma unroll
  for (int dt = 0; dt < 16; ++dt) {
    const int d = dt * 16 + h;
    s16x8 vf = *reinterpret_cast<const s16x8*>(VtB + d * 64 + ((16 * g) ^ (((dt ^ h) & 3) << 4)));
    acc[dt] = mfma16(pa, __builtin_bit_cast(bf16x8, vf), acc[dt]);
  }
  __builtin_amdgcn_s_setprio(0);
}

// ---- stage tile T: DMA of 2x16KB images, 256-thread group (R13 verbatim) ----
__device__ __forceinline__
void stage_img32(const u16* KimgB, const u16* VimgB, int T,
                 char* KsB, char* VtB, int gl)
{
  const char* ks = (const char*)(KimgB + (size_t)T * 8192) + gl * 16;
  const char* vs = (const char*)(VimgB + (size_t)T * 8192) + gl * 16;
  #pragma unroll
  for (int i = 0; i < 4; ++i) {
    gload16(ks + i * 4096, KsB + gl * 16 + i * 4096);
    gload16(vs + i * 4096, VtB + gl * 16 + i * 4096);
  }
}

template<bool USE_WS>
__global__ __launch_bounds__(1024)
__attribute__((amdgpu_waves_per_eu(4, 4)))
void attn_fwd_kernel(const float* __restrict__ Qg, const void* __restrict__ Kp,
                     const void* __restrict__ Vp, float* __restrict__ Og)
{
  __shared__ __align__(16) char smem[132096];  // 4 grp x 32KB + 1KB ml

  const int wg   = blockIdx.x;                 // 256 WGs (1 per CU)
  const int swz  = (wg & 7) * 32 + (wg >> 3);  // bijective XCD swizzle
  const int b    = swz >> 6;
  const int qt   = swz & 63;
  const int tid  = threadIdx.x;
  const int wave = tid >> 6;                   // 0..15
  const int lane = tid & 63;
  const int g    = lane >> 4;
  const int h    = lane & 15;
  const int gid  = wave >> 2;                  // group 0..3
  const int wq   = wave & 3;                   // q-slot within group
  const int ltid = tid & 255;                  // intra-group thread id

  char* KsB = smem + gid * 32768;
  char* VtB = KsB + 16384;
  float2* mlS = reinterpret_cast<float2*>(smem + 131072);

  const int qbase = qt * 64 + wq * 16;

  // Q fragments (B-operand of swapped QK^T), pre-scaled by 1/sqrt(256)
  bf16x8 qf[8];
  {
    const float* qrow = Qg + ((size_t)b * S_LEN + qbase + h) * D_DIM;
    #pragma unroll
    for (int dc = 0; dc < 8; ++dc) {
      float4 f0 = *reinterpret_cast<const float4*>(qrow + dc * 32 + g * 8);
      float4 f1 = *reinterpret_cast<const float4*>(qrow + dc * 32 + g * 8 + 4);
      bf16x8 q;
      q[0] = (__bf16)(f0.x * 0.0625f); q[1] = (__bf16)(f0.y * 0.0625f);
      q[2] = (__bf16)(f0.z * 0.0625f); q[3] = (__bf16)(f0.w * 0.0625f);
      q[4] = (__bf16)(f1.x * 0.0625f); q[5] = (__bf16)(f1.y * 0.0625f);
      q[6] = (__bf16)(f1.z * 0.0625f); q[7] = (__bf16)(f1.w * 0.0625f);
      qf[dc] = q;
    }
  }

  f32x4 acc[16];
  const f32x4 fz = {0.f, 0.f, 0.f, 0.f};
  #pragma unroll
  for (int i = 0; i < 16; ++i) acc[i] = fz;
  float m_run = -1e30f;
  float l_run = 0.f;

  const int cp    = (gid & 1) ^ (gid >> 1);   // compute parity (anti-phased)
  const int tbase = (gid >> 1) * 64;          // pair key range base (tiles)

  if constexpr (USE_WS) {
    const u16* KimgB = (const u16*)Kp + (size_t)b * 128 * 8192;
    const u16* VimgB = (const u16*)Vp + (size_t)b * 128 * 8192;

    // ---- prologue: cp==0 groups stage their first tile ----
    if (cp == 0) stage_img32(KimgB, VimgB, tbase, KsB, VtB, ltid);
    __syncthreads();

    // ---- main loop: 1 barrier per half-step (R11 schedule, 16 waves) ----
    for (int hs = 0; hs < NHS; ++hs) {
      if ((hs & 1) == cp)
        compute_tile32(KsB, VtB, qf, acc, m_run, l_run, g, h);
      else if (hs < NHS - 1)
        stage_img32(KimgB, VimgB, tbase + hs + 1, KsB, VtB, ltid);
      __syncthreads();
    }

  } else {
    // fallback (fp32 inputs, serial staging; R13-fallback roles per group)
    const float* Kf = (const float*)Kp + (size_t)b * S_LEN * D_DIM;
    const float* Vf = (const float*)Vp + (size_t)b * S_LEN * D_DIM;
    const int rk = (ltid & 127) >> 2, ck = ltid & 3;
    const int kb = ltid & 7, dcq = (ltid & 127) >> 3;
    const int Xw = 16 * (kb & 3) + 8 * (kb >> 2);
    for (int s = 0; s < 32; ++s) {
      const int tile = tbase + 2 * s + cp;
      __syncthreads();
      if (ltid < 128) {
        #pragma unroll
        for (int i = 0; i < 8; ++i) {
          const float* src = Kf + (size_t)(tile * KVBLK + rk) * D_DIM + ck * 64 + i * 8;
          float4 f0 = *reinterpret_cast<const float4*>(src);
          float4 f1 = *reinterpret_cast<const float4*>(src + 4);
          char* dst = KsB + rk * 512 + ((ck * 128 + i * 16) ^ ((rk & 7) << 4));
          *reinterpret_cast<s16x4*>(dst)     = cvt4(f0.x, f0.y, f0.z, f0.w);
          *reinterpret_cast<s16x4*>(dst + 8) = cvt4(f1.x, f1.y, f1.z, f1.w);
        }
      } else {
        s16x8 lo[4], hi[4];
        #pragma unroll
        for (int r = 0; r < 4; ++r) {
          const float* src = Vf + (size_t)(tile * KVBLK + kb * 4 + r) * D_DIM + dcq * 16;
          float4 f0 = *reinterpret_cast<const float4*>(src);
          float4 f1 = *reinterpret_cast<const float4*>(src + 4);
          float4 f2 = *reinterpret_cast<const float4*>(src + 8);
          float4 f3 = *reinterpret_cast<const float4*>(src + 12);
          lo[r] = __builtin_shufflevector(cvt4(f0.x, f0.y, f0.z, f0.w),
                                          cvt4(f1.x, f1.y, f1.z, f1.w), 0, 1, 2, 3, 4, 5, 6, 7);
          hi[r] = __builtin_shufflevector(cvt4(f2.x, f2.y, f2.z, f2.w),
                                          cvt4(f3.x, f3.y, f3.z, f3.w), 0, 1, 2, 3, 4, 5, 6, 7);
        }
        #pragma unroll
        for (int j = 0; j < 8; ++j) {
          s16x4 c0, c1;
          c0[0] = lo[0][j]; c0[1] = lo[1][j]; c0[2] = lo[2][j]; c0[3] = lo[3][j];
          c1[0] = hi[0][j]; c1[1] = hi[1][j]; c1[2] = hi[2][j]; c1[3] = hi[3][j];
          const int d0 = dcq * 16 + j;
          const int d1 = d0 + 8;
          *reinterpret_cast<s16x4*>(VtB + d0 * 64 + (Xw ^ ((((d0 >> 4) ^ d0) & 3) << 4))) = c0;
          *reinterpret_cast<s16x4*>(VtB + d1 * 64 + (Xw ^ ((((d1 >> 4) ^ d1) & 3) << 4))) = c1;
        }
      }
      __syncthreads();
      compute_tile32(KsB, VtB, qf, acc, m_run, l_run, g, h);
    }
  }

  // ---- 4-way split-K merge, 2 rounds (R16 verbatim, verified) ----
  __syncthreads();   // all compute done; tile buffers are now dead
  // round 1: groups 2,3 (waves 8..15) store (m,l,acc) into blocks 0..7
  if (gid >= 2) {
    const int w8 = wave - 8;
    char* base = smem + w8 * 16384 + lane * 256;
    #pragma unroll
    for (int dt = 0; dt < 16; ++dt)
      *reinterpret_cast<f32x4*>(base + (dt * 16 ^ ((lane & 7) << 4))) = acc[dt];
    if (g == 0) { float2 ml; ml.x = m_run; ml.y = l_run; mlS[w8 * 16 + h] = ml; }
  }
  __syncthreads();
  // round 1 merge: waves 0..7 absorb partner wave+8 (same wq, group gid+2)
  if (gid < 2) {
    const float2 ml = mlS[wave * 16 + h];
    const float mB = ml.x, lB = ml.y;
    const float mN = fmaxf(m_run, mB);
    const float sA = __expf(m_run - mN);
    const float sB = __expf(mB - mN);
    l_run = l_run * sA + lB * sB;
    m_run = mN;
    float aA[4], aB[4];
    #pragma unroll
    for (int r = 0; r < 4; ++r) { aA[r] = __shfl(sA, g * 4 + r); aB[r] = __shfl(sB, g * 4 + r); }
    const char* base = smem + wave * 16384 + lane * 256;
    #pragma unroll
    for (int dt = 0; dt < 16; ++dt) {
      f32x4 ab = *reinterpret_cast<const f32x4*>(base + (dt * 16 ^ ((lane & 7) << 4)));
      acc[dt][0] = acc[dt][0] * aA[0] + ab[0] * aB[0];
      acc[dt][1] = acc[dt][1] * aA[1] + ab[1] * aB[1];
      acc[dt][2] = acc[dt][2] * aA[2] + ab[2] * aB[2];
      acc[dt][3] = acc[dt][3] * aA[3] + ab[3] * aB[3];
    }
  }
  __syncthreads();
  // round 2: group 1 (waves 4..7) stores merged state into blocks 0..3
  if (gid == 1) {
    const int w4 = wave - 4;
    char* base = smem + w4 * 16384 + lane * 256;
    #pragma unroll
    for (int dt = 0; dt < 16; ++dt)
      *reinterpret_cast<f32x4*>(base + (dt * 16 ^ ((lane & 7) << 4))) = acc[dt];
    if (g == 0) { float2 ml; ml.x = m_run; ml.y = l_run; mlS[w4 * 16 + h] = ml; }
  }
  __syncthreads();
  // round 2 merge + epilogue: group 0 (waves 0..3) writes O
  if (gid == 0) {
    const float2 ml = mlS[wave * 16 + h];
    const float mB = ml.x, lB = ml.y;
    const float mN = fmaxf(m_run, mB);
    const float sA = __expf(m_run - mN);
    const float sB = __expf(mB - mN);
    const float lN = l_run * sA + lB * sB;
    float aA[4], aB[4], inv[4];
    #pragma unroll
    for (int r = 0; r < 4; ++r) {
      aA[r]  = __shfl(sA, g * 4 + r);
      aB[r]  = __shfl(sB, g * 4 + r);
      inv[r] = 1.f / __shfl(lN, g * 4 + r);
    }
    const char* base = smem + wave * 16384 + lane * 256;
    float* orow0 = Og + ((size_t)b * S_LEN + qbase) * D_DIM;
    #pragma unroll
    for (int dt = 0; dt < 16; ++dt) {
      f32x4 ab = *reinterpret_cast<const f32x4*>(base + (dt * 16 ^ ((lane & 7) << 4)));
      orow0[(size_t)(g * 4 + 0) * D_DIM + h + dt * 16] = (acc[dt][0] * aA[0] + ab[0] * aB[0]) * inv[0];
      orow0[(size_t)(g * 4 + 1) * D_DIM + h + dt * 16] = (acc[dt][1] * aA[1] + ab[1] * aB[1]) * inv[1];
      orow0[(size_t)(g * 4 + 2) * D_DIM + h + dt * 16] = (acc[dt][2] * aA[2] + ab[2] * aB[2]) * inv[2];
      orow0[(size_t)(g * 4 + 3) * D_DIM + h + dt * 16] = (acc[dt][3] * aA[3] + ab[3] * aB[3]) * inv[3];
    }
  }
}

extern "C" void kernel_launch(void* const* d_in, const int* in_sizes, int n_in,
                              void* d_out, int out_size, void* d_ws, size_t ws_size,
                              hipStream_t stream)
{
  const float* Q = (const float*)d_in[0];
  const float* K = (const float*)d_in[1];
  const float* V = (const float*)d_in[2];
  float* O = (float*)d_out;

  const size_t nelem = (size_t)NBATCH * S_LEN * D_DIM;   // 4,194,304
  const size_t need  = 2 * nelem * sizeof(u16);          // 16 MiB

  if (ws_size >= need) {
    u16* Kimg = (u16*)d_ws;                 // 4 batches x 128 tiles x 8192 u16
    u16* Vimg = Kimg + nelem;
    build_imgs32<<<512, 256, 0, stream>>>(K, V, Kimg, Vimg);
    attn_fwd_kernel<true><<<256, 1024, 0, stream>>>(Q, (const void*)Kimg, (const void*)Vimg, O);
  } else {
    attn_fwd_kernel<false><<<256, 1024, 0, stream>>>(Q, (const void*)K, (const void*)V, O);
  }
}

// Round 19
// 123.504 us; speedup vs baseline: 1.5150x; 1.5150x over previous
//
#include <hip/hip_runtime.h>
#include <hip/hip_bf16.h>
#include <stdint.h>

#define S_LEN 4096
#define D_DIM 256
#define NBATCH 4
#define NSUP 32   // super-steps: group A computes tiles 2s, group B tiles 2s+1

typedef unsigned short u16;
typedef float  f32x4  __attribute__((ext_vector_type(4)));
typedef __bf16 bf16x8 __attribute__((ext_vector_type(8)));
typedef __bf16 bf16x4 __attribute__((ext_vector_type(4)));
typedef short  s16x8  __attribute__((ext_vector_type(8)));
typedef short  s16x4  __attribute__((ext_vector_type(4)));

#define AS1 __attribute__((address_space(1)))
#define AS3 __attribute__((address_space(3)))

__device__ __forceinline__ f32x4 mfma16(bf16x8 a, bf16x8 b, f32x4 c) {
  return __builtin_amdgcn_mfma_f32_16x16x32_bf16(a, b, c, 0, 0, 0);
}

__device__ __forceinline__ s16x4 cvt4(float x, float y, float z, float w) {
  bf16x4 b;
  b[0] = (__bf16)x; b[1] = (__bf16)y; b[2] = (__bf16)z; b[3] = (__bf16)w;
  return __builtin_bit_cast(s16x4, b);
}

__device__ __forceinline__ void gload16(const void* g, void* l) {
  __builtin_amdgcn_global_load_lds((const AS1 unsigned int*)g,
                                   (AS3 unsigned int*)l, 16, 0, 0);
}

// ---------------------------------------------------------------------------
// R19 = R15 verbatim (124.53us, best validated kernel of the session).
// Structure: 8-wave WG (1/CU), 2 split-K groups x 4 q-waves; R9 alternation
// (one group computes its staged 64-key tile while the other DMAs its next
// tile image from d_ws); fused image pre-pass builds exact LDS byte images
// (K row-swizzled, V transposed + column-permuted + swizzled) once per tile.
// Image formulas (verified):
//  K image: row k (64), chunk p (32x16B): content = K[k][8*(p^(k&7)) .. +8]
//  V image: row d (256), byte position (2*col(k)) ^ ((d&7)<<4) holds V[k][d],
//           col(k) = 16*((k>>2)&3) + 4*(k>>4) + (k&3)
//  inverse: k = (col&3) + 4*(col>>4) + 16*((col>>2)&3)
// ---------------------------------------------------------------------------

__global__ void build_imgs(const float* __restrict__ K, const float* __restrict__ V,
                           u16* __restrict__ kimg, u16* __restrict__ vimg) {
  __shared__ u16 lds[64 * 264];            // V tile bf16, row stride 264 u16
  const int wg  = blockIdx.x;              // (b*64 + T), 256 WGs
  const int tid = threadIdx.x;

  // ---- K image ----
  const float* ksrc = K + (size_t)wg * 64 * D_DIM;
  u16*         kdst = kimg + (size_t)wg * 16384;
  #pragma unroll
  for (int i = 0; i < 8; ++i) {
    const int idx = i * 256 + tid;         // 2048 chunks of 16B
    const int k = idx >> 5, p = idx & 31;
    const int q = p ^ (k & 7);
    const float* s = ksrc + k * 256 + q * 8;
    float4 f0 = *reinterpret_cast<const float4*>(s);
    float4 f1 = *reinterpret_cast<const float4*>(s + 4);
    s16x8 v = __builtin_shufflevector(cvt4(f0.x, f0.y, f0.z, f0.w),
                                      cvt4(f1.x, f1.y, f1.z, f1.w),
                                      0, 1, 2, 3, 4, 5, 6, 7);
    *reinterpret_cast<s16x8*>(kdst + k * 256 + p * 8) = v;
  }

  // ---- V image ----
  const float* vsrc = V + (size_t)wg * 64 * D_DIM;
  u16*         vdst = vimg + (size_t)wg * 16384;
  #pragma unroll
  for (int i = 0; i < 8; ++i) {
    const int idx = i * 256 + tid;
    const int k = idx >> 5, q = idx & 31;  // q: 8-elem d chunk
    const float* s = vsrc + k * 256 + q * 8;
    float4 f0 = *reinterpret_cast<const float4*>(s);
    float4 f1 = *reinterpret_cast<const float4*>(s + 4);
    s16x8 v = __builtin_shufflevector(cvt4(f0.x, f0.y, f0.z, f0.w),
                                      cvt4(f1.x, f1.y, f1.z, f1.w),
                                      0, 1, 2, 3, 4, 5, 6, 7);
    *reinterpret_cast<s16x8*>(&lds[k * 264 + q * 8]) = v;
  }
  __syncthreads();
  #pragma unroll
  for (int i = 0; i < 8; ++i) {
    const int idx = i * 256 + tid;         // 2048 output chunks of 16B
    const int d = idx >> 3, c = idx & 7;
    const int cp = c ^ (d & 7);
    s16x8 o;
    #pragma unroll
    for (int j = 0; j < 8; ++j) {
      const int col = 8 * cp + j;
      const int k = (col & 3) + 4 * (col >> 4) + 16 * ((col >> 2) & 3);
      o[j] = (short)lds[k * 264 + d];
    }
    *reinterpret_cast<s16x8*>(vdst + d * 64 + c * 8) = o;
  }
}

// ---- compute one staged tile from LDS ----
__device__ __forceinline__
void compute_tile(const char* KsB, const char* vpA, const char* vpB,
                  const bf16x8 (&qf)[8], f32x4 (&acc)[16],
                  float& m_run, float& l_run, int g, int h)
{
  const f32x4 fz = {0.f, 0.f, 0.f, 0.f};

  f32x4 st[4];
  __builtin_amdgcn_s_setprio(1);
  #pragma unroll
  for (int t = 0; t < 4; ++t) {
    f32x4 a = fz;
    const int row = t * 16 + h;
    const int sw  = (row & 7) << 4;
    #pragma unroll
    for (int dc = 0; dc < 8; ++dc) {
      s16x8 kfrag = *reinterpret_cast<const s16x8*>(KsB + row * 512 + ((dc * 64 + g * 16) ^ sw));
      a = mfma16(__builtin_bit_cast(bf16x8, kfrag), qf[dc], a);
    }
    st[t] = a;
  }
  __builtin_amdgcn_s_setprio(0);

  float sv[16];
  #pragma unroll
  for (int t = 0; t < 4; ++t) {
    sv[t * 4 + 0] = st[t][0]; sv[t * 4 + 1] = st[t][1];
    sv[t * 4 + 2] = st[t][2]; sv[t * 4 + 3] = st[t][3];
  }
  float tmax = sv[0];
  #pragma unroll
  for (int i = 1; i < 16; ++i) tmax = fmaxf(tmax, sv[i]);
  tmax = fmaxf(tmax, __shfl_xor(tmax, 16));
  tmax = fmaxf(tmax, __shfl_xor(tmax, 32));

  if (!__all(tmax <= m_run + 8.0f)) {     // T13 defer-max
    const float mnew  = fmaxf(m_run, tmax);
    const float alpha = __expf(m_run - mnew);
    l_run *= alpha;
    const float af0 = __shfl(alpha, g * 4 + 0);
    const float af1 = __shfl(alpha, g * 4 + 1);
    const float af2 = __shfl(alpha, g * 4 + 2);
    const float af3 = __shfl(alpha, g * 4 + 3);
    #pragma unroll
    for (int dt = 0; dt < 16; ++dt) {
      acc[dt][0] *= af0; acc[dt][1] *= af1; acc[dt][2] *= af2; acc[dt][3] *= af3;
    }
    m_run = mnew;
  }

  float psum = 0.f;
  #pragma unroll
  for (int i = 0; i < 16; ++i) { sv[i] = __expf(sv[i] - m_run); psum += sv[i]; }
  psum += __shfl_xor(psum, 16);
  psum += __shfl_xor(psum, 32);
  l_run += psum;

  bf16x8 pa0, pa1;
  #pragma unroll
  for (int j = 0; j < 8; ++j) { pa0[j] = (__bf16)sv[j]; pa1[j] = (__bf16)sv[8 + j]; }

  __builtin_amdgcn_s_setprio(1);
  #pragma unroll
  for (int dt = 0; dt < 16; ++dt) {
    s16x8 v0 = *reinterpret_cast<const s16x8*>(vpA + dt * 2048);
    s16x8 v1 = *reinterpret_cast<const s16x8*>(vpB + dt * 2048);
    acc[dt] = mfma16(pa0, __builtin_bit_cast(bf16x8, v0), acc[dt]);
    acc[dt] = mfma16(pa1, __builtin_bit_cast(bf16x8, v1), acc[dt]);
  }
  __builtin_amdgcn_s_setprio(0);
}

// ---- stage tile T: pure DMA copy of the 2x32KB images ----
__device__ __forceinline__
void stage_img(const u16* KimgB, const u16* VimgB, int T,
               char* KsB, char* VtB, int w, int lane)
{
  const char* ks = (const char*)(KimgB + (size_t)T * 16384) + lane * 16;
  const char* vs = (const char*)(VimgB + (size_t)T * 16384) + lane * 16;
  #pragma unroll
  for (int i = 0; i < 8; ++i) {
    const int off = (i * 4 + w) * 1024;
    gload16(ks + off, KsB + off);
    gload16(vs + off, VtB + off);
  }
}

template<bool USE_WS>
__global__ __launch_bounds__(512, 1)
void attn_fwd_kernel(const float* __restrict__ Qg, const void* __restrict__ Kp,
                     const void* __restrict__ Vp, float* __restrict__ Og)
{
  __shared__ __align__(16) char smem[131072];   // 2 x (32KB Ks + 32KB Vt)

  const int wg   = blockIdx.x;                  // 256 WGs (1 per CU)
  const int swz  = (wg & 7) * 32 + (wg >> 3);   // bijective XCD swizzle
  const int b    = swz >> 6;
  const int qt   = swz & 63;
  const int tid  = threadIdx.x;
  const int wave = tid >> 6;                    // 0..7
  const int lane = tid & 63;
  const int g    = lane >> 4;
  const int h    = lane & 15;
  const int gid  = tid >> 8;                    // 0 = group A, 1 = group B
  const int ltid = tid & 255;                   // intra-group thread id
  const int wq   = wave & 3;                    // q-slot within group
  const int w    = wave & 3;                    // wave index within group

  const int kb  = ltid & 15;                    // (fallback staging roles)
  const int dcq = ltid >> 4;
  const int Xw  = 32 * (kb & 3) + 8 * (kb >> 2);

  char* KsB = smem + gid * 65536;
  char* VtB = KsB + 32768;

  const int qbase = qt * 64 + wq * 16;

  // Q fragments (B-operand of swapped QK^T), pre-scaled by 1/sqrt(256)
  bf16x8 qf[8];
  {
    const float* qrow = Qg + ((size_t)b * S_LEN + qbase + h) * D_DIM;
    #pragma unroll
    for (int dc = 0; dc < 8; ++dc) {
      float4 f0 = *reinterpret_cast<const float4*>(qrow + dc * 32 + g * 8);
      float4 f1 = *reinterpret_cast<const float4*>(qrow + dc * 32 + g * 8 + 4);
      bf16x8 q;
      q[0] = (__bf16)(f0.x * 0.0625f); q[1] = (__bf16)(f0.y * 0.0625f);
      q[2] = (__bf16)(f0.z * 0.0625f); q[3] = (__bf16)(f0.w * 0.0625f);
      q[4] = (__bf16)(f1.x * 0.0625f); q[5] = (__bf16)(f1.y * 0.0625f);
      q[6] = (__bf16)(f1.z * 0.0625f); q[7] = (__bf16)(f1.w * 0.0625f);
      qf[dc] = q;
    }
  }

  f32x4 acc[16];
  const f32x4 fz = {0.f, 0.f, 0.f, 0.f};
  #pragma unroll
  for (int i = 0; i < 16; ++i) acc[i] = fz;
  float m_run = -1e30f;
  float l_run = 0.f;

  const char* vpA = VtB + h * 128 + ((32 * g)      ^ ((h & 7) << 4));
  const char* vpB = VtB + h * 128 + ((32 * g + 16) ^ ((h & 7) << 4));

  if constexpr (USE_WS) {
    const u16* KimgB = (const u16*)Kp + (size_t)b * 64 * 16384;
    const u16* VimgB = (const u16*)Vp + (size_t)b * 64 * 16384;

    // ---- prologue: group A stages tile 0 ----
    if (gid == 0) stage_img(KimgB, VimgB, 0, KsB, VtB, w, lane);
    __syncthreads();

    // ---- alternating main loop: 1 barrier per half-step ----
    for (int s = 0; s < NSUP; ++s) {
      // half-step 2s: A computes tile 2s, B stages tile 2s+1
      if (gid == 0) compute_tile(KsB, vpA, vpB, qf, acc, m_run, l_run, g, h);
      else          stage_img(KimgB, VimgB, 2 * s + 1, KsB, VtB, w, lane);
      __syncthreads();
      // half-step 2s+1: B computes tile 2s+1, A stages tile 2s+2
      if (gid == 0) { if (s < NSUP - 1) stage_img(KimgB, VimgB, 2 * s + 2, KsB, VtB, w, lane); }
      else          compute_tile(KsB, vpA, vpB, qf, acc, m_run, l_run, g, h);
      __syncthreads();
    }

  } else {
    // fallback (fp32 inputs, serial staging) — used only if d_ws is too small
    const float* Kf = (const float*)Kp + (size_t)b * S_LEN * D_DIM;
    const float* Vf = (const float*)Vp + (size_t)b * S_LEN * D_DIM;
    for (int s = 0; s < NSUP; ++s) {
      const int kt = 2 * s + gid;
      __syncthreads();
      #pragma unroll
      for (int i = 0; i < 16; ++i) {
        int flat = i * 256 + ltid;
        int kk = flat >> 6;
        int d  = (flat & 63) * 4;
        float4 fk = *reinterpret_cast<const float4*>(Kf + (size_t)(kt * 64 + kk) * D_DIM + d);
        *reinterpret_cast<s16x4*>(KsB + kk * 512 + ((d * 2) ^ ((kk & 7) << 4))) = cvt4(fk.x, fk.y, fk.z, fk.w);
      }
      {
        s16x8 lo[4], hi[4];
        #pragma unroll
        for (int r = 0; r < 4; ++r) {
          const float* src = Vf + (size_t)(kt * 64 + kb * 4 + r) * D_DIM + dcq * 16;
          float4 f0 = *reinterpret_cast<const float4*>(src);
          float4 f1 = *reinterpret_cast<const float4*>(src + 4);
          float4 f2 = *reinterpret_cast<const float4*>(src + 8);
          float4 f3 = *reinterpret_cast<const float4*>(src + 12);
          lo[r] = __builtin_shufflevector(cvt4(f0.x, f0.y, f0.z, f0.w),
                                          cvt4(f1.x, f1.y, f1.z, f1.w), 0, 1, 2, 3, 4, 5, 6, 7);
          hi[r] = __builtin_shufflevector(cvt4(f2.x, f2.y, f2.z, f2.w),
                                          cvt4(f3.x, f3.y, f3.z, f3.w), 0, 1, 2, 3, 4, 5, 6, 7);
        }
        #pragma unroll
        for (int j = 0; j < 8; ++j) {
          s16x4 c0, c1;
          c0[0] = lo[0][j]; c0[1] = lo[1][j]; c0[2] = lo[2][j]; c0[3] = lo[3][j];
          c1[0] = hi[0][j]; c1[1] = hi[1][j]; c1[2] = hi[2][j]; c1[3] = hi[3][j];
          const int d0 = dcq * 16 + j;
          const int d1 = d0 + 8;
          *reinterpret_cast<s16x4*>(VtB + d0 * 128 + (Xw ^ ((d0 & 7) << 4))) = c0;
          *reinterpret_cast<s16x4*>(VtB + d1 * 128 + (Xw ^ ((d1 & 7) << 4))) = c1;
        }
      }
      __syncthreads();
      compute_tile(KsB, vpA, vpB, qf, acc, m_run, l_run, g, h);
    }
  }

  // ---- merge group B's state into group A, then epilogue ----
  __syncthreads();   // all compute done; tile buffers are now dead
  float2* mlM = reinterpret_cast<float2*>(smem + 65536);
  if (gid == 1) {
    const int bw = wave - 4;
    char* base = smem + bw * 16384 + lane * 256;
    #pragma unroll
    for (int dt = 0; dt < 16; ++dt) {
      float4 v; v.x = acc[dt][0]; v.y = acc[dt][1]; v.z = acc[dt][2]; v.w = acc[dt][3];
      *reinterpret_cast<float4*>(base + (dt * 16 ^ ((lane & 7) << 4))) = v;
    }
    if (g == 0) { float2 ml; ml.x = m_run; ml.y = l_run; mlM[bw * 16 + h] = ml; }
  }
  __syncthreads();
  if (gid == 0) {
    const float2 ml = mlM[wave * 16 + h];
    const float mB = ml.x, lB = ml.y;
    const float m  = fmaxf(m_run, mB);
    const float sA = __expf(m_run - m);
    const float sB = __expf(mB - m);
    const float l  = l_run * sA + lB * sB;
    float aA[4], aB[4], inv[4];
    #pragma unroll
    for (int r = 0; r < 4; ++r) {
      aA[r]  = __shfl(sA, g * 4 + r);
      aB[r]  = __shfl(sB, g * 4 + r);
      inv[r] = 1.f / __shfl(l, g * 4 + r);
    }
    const char* base = smem + wave * 16384 + lane * 256;
    float* orow0 = Og + ((size_t)b * S_LEN + qbase) * D_DIM;
    #pragma unroll
    for (int dt = 0; dt < 16; ++dt) {
      float4 ab = *reinterpret_cast<const float4*>(base + (dt * 16 ^ ((lane & 7) << 4)));
      orow0[(size_t)(g * 4 + 0) * D_DIM + h + dt * 16] = (acc[dt][0] * aA[0] + ab.x * aB[0]) * inv[0];
      orow0[(size_t)(g * 4 + 1) * D_DIM + h + dt * 16] = (acc[dt][1] * aA[1] + ab.y * aB[1]) * inv[1];
      orow0[(size_t)(g * 4 + 2) * D_DIM + h + dt * 16] = (acc[dt][2] * aA[2] + ab.z * aB[2]) * inv[2];
      orow0[(size_t)(g * 4 + 3) * D_DIM + h + dt * 16] = (acc[dt][3] * aA[3] + ab.w * aB[3]) * inv[3];
    }
  }
}

extern "C" void kernel_launch(void* const* d_in, const int* in_sizes, int n_in,
                              void* d_out, int out_size, void* d_ws, size_t ws_size,
                              hipStream_t stream)
{
  const float* Q = (const float*)d_in[0];
  const float* K = (const float*)d_in[1];
  const float* V = (const float*)d_in[2];
  float* O = (float*)d_out;

  const size_t nelem = (size_t)NBATCH * S_LEN * D_DIM;   // 4,194,304
  const size_t need  = 2 * nelem * sizeof(u16);          // 16 MiB

  if (ws_size >= need) {
    u16* Kimg = (u16*)d_ws;                 // 4 batches x 64 tiles x 16384 u16
    u16* Vimg = Kimg + nelem;
    build_imgs<<<256, 256, 0, stream>>>(K, V, Kimg, Vimg);
    attn_fwd_kernel<true><<<256, 512, 0, stream>>>(Q, (const void*)Kimg, (const void*)Vimg, O);
  } else {
    attn_fwd_kernel<false><<<256, 512, 0, stream>>>(Q, (const void*)K, (const void*)V, O);
  }
}